// Round 7
// baseline (5913.372 us; speedup 1.0000x reference)
//
#include <hip/hip_runtime.h>
#include <hip/hip_bf16.h>
#include <math.h>

#define B_   128
#define S_   1024
#define I_   512
#define H_   1024
#define KC   1536
#define NWG  256
#define NTHR 512
#define XLD  528    // x-panel row stride (512+16): 264 dw % 32 banks = 8 -> balanced
#define HLD  1040   // h-panel row stride (1024+16): 520 dw % 32 = 8 -> balanced

typedef __bf16 v8bf __attribute__((ext_vector_type(8)));
typedef float  v4f  __attribute__((ext_vector_type(4)));
typedef unsigned long long ull;

__device__ __forceinline__ v8bf cvt8(const float4 a, const float4 b) {
    v8bf r;
    r[0] = (__bf16)a.x; r[1] = (__bf16)a.y; r[2] = (__bf16)a.z; r[3] = (__bf16)a.w;
    r[4] = (__bf16)b.x; r[5] = (__bf16)b.y; r[6] = (__bf16)b.z; r[7] = (__bf16)b.w;
    return r;
}

__device__ __forceinline__ float sigm(float x) { return 1.f / (1.f + __expf(-x)); }
__device__ __forceinline__ float tanh_fast(float x) {
    const float xc = fminf(fmaxf(x, -15.f), 15.f);
    const float e  = __expf(2.f * xc);
    return (e - 1.f) / (e + 1.f);
}

// Pack W_ih||W_hh (fp32) -> Wc bf16 [4096][1536] row-major. 8 elems/thread.
__global__ void lstm_pack(const float* __restrict__ Wih, const float* __restrict__ Whh,
                          __bf16* __restrict__ Wc)
{
    const size_t e = ((size_t)blockIdx.x * 256 + threadIdx.x) * 8;
    const int col = (int)(e / KC);
    const int k   = (int)(e % KC);
    const float4* src = (k < I_) ? (const float4*)&Wih[(size_t)col * I_ + k]
                                 : (const float4*)&Whh[(size_t)col * H_ + (k - I_)];
    const float4 a = src[0], b = src[1];
    *(v8bf*)&Wc[e] = cvt8(a, b);
}

// Persistent LSTM. 256 WGs = 4 batch-groups (bg=wg&3, 32 rows each) x 64
// col-groups (cg=wg>>2, 16 h-cols each). 8 waves/WG: wave (g,ks) = gate g,
// k-half ks; N-tile = 16 gate-cols, M = 2x16 rows, 24 resident weight v8bf
// (96 VGPR). Total reg demand ~210 < 256 -> weights stay in registers.
__global__ __launch_bounds__(NTHR, 1) void lstm_persist(
    const float* __restrict__ seq, const int* __restrict__ len,
    const __bf16* __restrict__ Wc,
    const float* __restrict__ bih, const float* __restrict__ bhh,
    float* __restrict__ out, __bf16* __restrict__ hA, __bf16* __restrict__ hB,
    unsigned* __restrict__ cnt)
{
    __shared__ __bf16 xpan[2][32 * XLD];   // double-buffered x_t (prefetched)
    __shared__ __bf16 hpan[32 * HLD];      // h_{t-1}
    __shared__ float  glds[4][2][32][18];  // [gate][k-half][row][col+pad]

    const int wg   = blockIdx.x;
    const int bg   = wg & 3;     // batch group: rows bg*32+[0,32)
    const int cg   = wg >> 2;    // col group: h-cols cg*16+[0,16)
    const int tid  = threadIdx.x;
    const int lane = tid & 63;
    const int wv   = tid >> 6;
    const int l15  = lane & 15;
    const int q    = lane >> 4;
    const int g    = wv >> 1;    // gate i,f,g,o
    const int ks   = wv & 1;     // k-half

    const int col = g * H_ + cg * 16 + l15;   // this lane's gate-col

    // ---- one-time: 24 weight v8bf (96 VGPR) resident for the whole kernel ----
    v8bf w[24];
    {
        const __bf16* wr = Wc + (size_t)col * KC;
        #pragma unroll
        for (int j = 0; j < 8; ++j)
            w[j] = *(const v8bf*)(wr + ks * 256 + q * 8 + j * 32);
        #pragma unroll
        for (int j = 0; j < 16; ++j)
            w[8 + j] = *(const v8bf*)(wr + I_ + ks * 512 + q * 8 + j * 32);
        #pragma unroll
        for (int j = 0; j < 24; ++j) asm volatile("" : "+v"(w[j]));
    }
    const float b0 = ks ? 0.f : (bih[col] + bhh[col]);

    // ---- per-thread cell (1 of 32x16) ----
    const int cb  = tid >> 4;    // row [0,32)
    const int ccc = tid & 15;    // h-col [0,16)
    const int gb  = bg * 32 + cb;
    const int gc  = cg * 16 + ccc;
    const int mylen = len[gb];
    float creg = 0.f;

    const float* xrow = seq + (size_t)gb * (S_ * I_);  // row cb == tid>>4

    // ---- prologue: stage x_0 ----
    {
        const float4* xs = (const float4*)xrow;
        #pragma unroll
        for (int jj = 0; jj < 4; ++jj) {
            const int fi = 2 * ccc + 32 * jj;
            const float4 a = xs[fi], b = xs[fi + 1];
            *(v8bf*)&xpan[0][cb * XLD + fi * 4] = cvt8(a, b);
        }
    }

    for (int t = 0; t < S_; ++t) {
        const int buf = t & 1;
        const __bf16* hrd = (t & 1) ? hA : hB;
        __bf16*       hwr = (t & 1) ? hB : hA;

        // ---- wait for h_{t-1} from all 64 WGs of this batch group ----
        if (t > 0 && tid == 0) {
            const unsigned* c0 = cnt + ((size_t)(t - 1) * 8) * 32 + bg;
            unsigned s;
            do {
                s = 0;
                #pragma unroll
                for (int u = 0; u < 8; ++u)
                    s += __hip_atomic_load(c0 + u * 32, __ATOMIC_RELAXED,
                                           __HIP_MEMORY_SCOPE_AGENT);
            } while (s < 64u);
        }
        __syncthreads();  // b1: x_t staged, h_{t-1} published

        // ---- issue h loads (coherent 8B atomics); hide under x-MFMA ----
        ull hv[16];
        {
            const ull* hs = (const ull*)(hrd + (size_t)(bg * 32) * H_);
            #pragma unroll
            for (int j = 0; j < 16; ++j)
                hv[j] = __hip_atomic_load(&hs[cb * 256 + ccc + 16 * j],
                                          __ATOMIC_RELAXED, __HIP_MEMORY_SCOPE_AGENT);
        }

        // ---- x-part MFMA (2 M-tiles x 8 k-tiles) ----
        v4f acc0 = {0.f, 0.f, 0.f, 0.f};
        v4f acc1 = {0.f, 0.f, 0.f, 0.f};
        {
            const __bf16* ap0 = &xpan[buf][l15 * XLD + ks * 256 + q * 8];
            const __bf16* ap1 = ap0 + 16 * XLD;
            #pragma unroll
            for (int j = 0; j < 8; ++j) {
                acc0 = __builtin_amdgcn_mfma_f32_16x16x32_bf16(
                           *(const v8bf*)(ap0 + j * 32), w[j], acc0, 0, 0, 0);
                acc1 = __builtin_amdgcn_mfma_f32_16x16x32_bf16(
                           *(const v8bf*)(ap1 + j * 32), w[j], acc1, 0, 0, 0);
            }
        }

        // ---- land h into LDS ----
        #pragma unroll
        for (int j = 0; j < 16; ++j)
            *(ull*)&hpan[cb * HLD + 4 * (ccc + 16 * j)] = hv[j];
        __syncthreads();  // b2: h panel ready

        // ---- issue x_{t+1} loads (prefetch), compute h-MFMA under them ----
        float4 xf[8];
        const bool pf = (t + 1 < S_);
        if (pf) {
            const float4* xs = (const float4*)(xrow + (size_t)(t + 1) * I_);
            #pragma unroll
            for (int jj = 0; jj < 4; ++jj) {
                const int fi = 2 * ccc + 32 * jj;
                xf[2 * jj]     = xs[fi];
                xf[2 * jj + 1] = xs[fi + 1];
            }
        }

        // ---- h-part MFMA (2 M-tiles x 16 k-tiles) ----
        {
            const __bf16* ap0 = &hpan[l15 * HLD + ks * 512 + q * 8];
            const __bf16* ap1 = ap0 + 16 * HLD;
            #pragma unroll
            for (int j = 0; j < 16; ++j) {
                acc0 = __builtin_amdgcn_mfma_f32_16x16x32_bf16(
                           *(const v8bf*)(ap0 + j * 32), w[8 + j], acc0, 0, 0, 0);
                acc1 = __builtin_amdgcn_mfma_f32_16x16x32_bf16(
                           *(const v8bf*)(ap1 + j * 32), w[8 + j], acc1, 0, 0, 0);
            }
        }

        // ---- store x_{t+1} into the other buffer ----
        if (pf) {
            #pragma unroll
            for (int jj = 0; jj < 4; ++jj) {
                const int fi = 2 * ccc + 32 * jj;
                *(v8bf*)&xpan[buf ^ 1][cb * XLD + fi * 4] =
                    cvt8(xf[2 * jj], xf[2 * jj + 1]);
            }
        }

        // ---- exchange gate pre-activations ----
        #pragma unroll
        for (int r = 0; r < 4; ++r) {
            glds[g][ks][q * 4 + r][l15]      = acc0[r] + b0;
            glds[g][ks][16 + q * 4 + r][l15] = acc1[r] + b0;
        }
        __syncthreads();  // b3

        // ---- cell update ----
        const float ig = glds[0][0][cb][ccc] + glds[0][1][cb][ccc];
        const float fg = glds[1][0][cb][ccc] + glds[1][1][cb][ccc];
        const float gg = glds[2][0][cb][ccc] + glds[2][1][cb][ccc];
        const float og = glds[3][0][cb][ccc] + glds[3][1][cb][ccc];

        const float cn = sigm(fg) * creg + sigm(ig) * tanh_fast(gg);
        const float hvv = sigm(og) * tanh_fast(cn);
        creg = cn;

        // ---- publish h_t (packed 4B relaxed agent stores) ----
        const unsigned short us = __builtin_bit_cast(unsigned short, (__bf16)hvv);
        const unsigned nb = __shfl_xor((unsigned)us, 1);
        if (!(tid & 1)) {
            const unsigned pair = (unsigned)us | (nb << 16);
            __hip_atomic_store((unsigned*)&hwr[(size_t)gb * H_ + gc], pair,
                               __ATOMIC_RELAXED, __HIP_MEMORY_SCOPE_AGENT);
        }
        if (t == mylen - 1) out[(size_t)gb * H_ + gc] = hvv;

        __syncthreads();  // b4: drains h stores (vmcnt(0) before s_barrier)
        if (tid == 0)
            __hip_atomic_fetch_add(cnt + ((size_t)t * 8 + (cg & 7)) * 32 + bg, 1u,
                                   __ATOMIC_RELAXED, __HIP_MEMORY_SCOPE_AGENT);
    }
}

extern "C" void kernel_launch(void* const* d_in, const int* in_sizes, int n_in,
                              void* d_out, int out_size, void* d_ws, size_t ws_size,
                              hipStream_t stream) {
    const float* seq = (const float*)d_in[0];
    const int*   len = (const int*)d_in[1];
    const float* Wih = (const float*)d_in[2];
    const float* Whh = (const float*)d_in[3];
    const float* bih = (const float*)d_in[4];
    const float* bhh = (const float*)d_in[5];
    float* out = (float*)d_out;

    char* ws = (char*)d_ws;
    __bf16*   Wc  = (__bf16*)ws;                          // 12,582,912 B
    __bf16*   hA  = (__bf16*)(ws + 12582912);             //    262,144 B
    __bf16*   hB  = (__bf16*)(ws + 12845056);             //    262,144 B
    unsigned* cnt = (unsigned*)(ws + 13107200);           //  1,048,576 B

    hipMemsetAsync(hA, 0, 2 * (size_t)B_ * H_ * sizeof(__bf16), stream);  // hA+hB
    hipMemsetAsync(cnt, 0, (size_t)S_ * 8 * 32 * sizeof(unsigned), stream);

    lstm_pack<<<dim3(3072), dim3(256), 0, stream>>>(Wih, Whh, Wc);

    void* args[] = {(void*)&seq, (void*)&len, (void*)&Wc, (void*)&bih,
                    (void*)&bhh, (void*)&out, (void*)&hA, (void*)&hB, (void*)&cnt};
    hipError_t e = hipLaunchCooperativeKernel((void*)lstm_persist, dim3(NWG),
                                              dim3(NTHR), args, 0, stream);
    if (e != hipSuccess) {
        lstm_persist<<<dim3(NWG), dim3(NTHR), 0, stream>>>(seq, len, Wc, bih,
                                                           bhh, out, hA, hB, cnt);
    }
}

// Round 8
// 5498.432 us; speedup vs baseline: 1.0755x; 1.0755x over previous
//
#include <hip/hip_runtime.h>
#include <hip/hip_bf16.h>
#include <math.h>

#define B_   128
#define S_   1024
#define I_   512
#define H_   1024
#define KC   1536
#define NWG  256
#define NTHR 512
#define XLD  520    // x-panel row stride bf16 (512+8): dw stride 260 %32==4 -> <=2-way b128
#define HLD  1032   // h-panel row stride bf16 (1024+8): dw stride 516 %32==4 -> <=2-way b128

typedef __bf16 v8bf __attribute__((ext_vector_type(8)));
typedef float  v4f  __attribute__((ext_vector_type(4)));
typedef unsigned long long ull;

__device__ __forceinline__ v8bf cvt8(const float4 a, const float4 b) {
    v8bf r;
    r[0] = (__bf16)a.x; r[1] = (__bf16)a.y; r[2] = (__bf16)a.z; r[3] = (__bf16)a.w;
    r[4] = (__bf16)b.x; r[5] = (__bf16)b.y; r[6] = (__bf16)b.z; r[7] = (__bf16)b.w;
    return r;
}

__device__ __forceinline__ float sigm(float x) { return 1.f / (1.f + __expf(-x)); }
__device__ __forceinline__ float tanh_fast(float x) {
    const float xc = fminf(fmaxf(x, -15.f), 15.f);
    const float e  = __expf(2.f * xc);
    return (e - 1.f) / (e + 1.f);
}

// Pack W_ih||W_hh (fp32) -> Wc bf16 [4096][1536] row-major.
__global__ void lstm_pack(const float* __restrict__ Wih, const float* __restrict__ Whh,
                          __bf16* __restrict__ Wc)
{
    const size_t e = ((size_t)blockIdx.x * 256 + threadIdx.x) * 8;
    const int col = (int)(e / KC);
    const int k   = (int)(e % KC);
    const float4* src = (k < I_) ? (const float4*)&Wih[(size_t)col * I_ + k]
                                 : (const float4*)&Whh[(size_t)col * H_ + (k - I_)];
    const float4 a = src[0], b = src[1];
    *(v8bf*)&Wc[e] = cvt8(a, b);
}

// Persistent LSTM. 256 WGs: bg=(wg&7)>>1 (4 batch groups, 32 rows, each on an
// adjacent XCD pair), cg=(wg>>3)*2|(wg&1) (64 col groups, 16 h-cols). Wave
// (g,ks): gate g, k-half ks. Weights: 24 v8bf/wave (96 regs, AGPR-resident;
// total demand ~210 < 256 -> no spill, proven by R7's VGPR=104).
// Pipelined: x-part MFMA for step t+1 runs after publishing h_t, so the poll
// and producer latency hide under it; per-step critical path = hv + h-MFMA.
__global__ __launch_bounds__(NTHR, 1) void lstm_persist(
    const float* __restrict__ seq, const int* __restrict__ len,
    const __bf16* __restrict__ Wc,
    const float* __restrict__ bih, const float* __restrict__ bhh,
    float* __restrict__ out, __bf16* __restrict__ hA, __bf16* __restrict__ hB,
    unsigned* __restrict__ cnt)
{
    __shared__ __bf16 xpan[2][32 * XLD];   // double-buffered x panels
    __shared__ __bf16 hpan[32 * HLD];      // h_{t-1}
    __shared__ float  glds[4][2][32][17];  // [gate][k-half][row][col+pad]

    const int wg   = blockIdx.x;
    const int bg   = (wg & 7) >> 1;          // batch group: rows bg*32+[0,32)
    const int cg   = ((wg >> 3) << 1) | (wg & 1);  // col group: h-cols cg*16+[0,16)
    const int tid  = threadIdx.x;
    const int lane = tid & 63;
    const int wv   = tid >> 6;
    const int l15  = lane & 15;
    const int q    = lane >> 4;
    const int g    = wv >> 1;    // gate i,f,g,o
    const int ks   = wv & 1;     // k-half

    const int col = g * H_ + cg * 16 + l15;  // this lane's gate-col

    // ---- one-time: 24 weight v8bf resident (AGPR) for the whole kernel ----
    v8bf w[24];
    {
        const __bf16* wr = Wc + (size_t)col * KC;
        #pragma unroll
        for (int j = 0; j < 8; ++j)
            w[j] = *(const v8bf*)(wr + ks * 256 + q * 8 + j * 32);
        #pragma unroll
        for (int j = 0; j < 16; ++j)
            w[8 + j] = *(const v8bf*)(wr + I_ + ks * 512 + q * 8 + j * 32);
        #pragma unroll
        for (int j = 0; j < 24; ++j) asm volatile("" : "+v"(w[j]));
    }
    const float b0 = ks ? 0.f : (bih[col] + bhh[col]);

    // ---- per-thread cell (1 of 32x16) ----
    const int cb  = tid >> 4;    // row [0,32)
    const int ccc = tid & 15;    // h-col [0,16)
    const int gb  = bg * 32 + cb;
    const int gc  = cg * 16 + ccc;
    const int mylen = len[gb];
    float creg = 0.f;

    const float* xrow = seq + (size_t)gb * (S_ * I_);

    // ---- prologue: stage x_0, compute accx(0) ----
    {
        const float4* xs = (const float4*)xrow;
        #pragma unroll
        for (int jj = 0; jj < 4; ++jj) {
            const int fi = 2 * ccc + 32 * jj;
            const float4 a = xs[fi], b = xs[fi + 1];
            *(v8bf*)&xpan[0][cb * XLD + fi * 4] = cvt8(a, b);
        }
    }
    __syncthreads();

    v4f accx0 = {0.f, 0.f, 0.f, 0.f};
    v4f accx1 = {0.f, 0.f, 0.f, 0.f};
    {
        const __bf16* ap0 = &xpan[0][l15 * XLD + ks * 256 + q * 8];
        const __bf16* ap1 = ap0 + 16 * XLD;
        #pragma unroll
        for (int j = 0; j < 8; ++j) {
            accx0 = __builtin_amdgcn_mfma_f32_16x16x32_bf16(
                        *(const v8bf*)(ap0 + j * 32), w[j], accx0, 0, 0, 0);
            accx1 = __builtin_amdgcn_mfma_f32_16x16x32_bf16(
                        *(const v8bf*)(ap1 + j * 32), w[j], accx1, 0, 0, 0);
        }
    }

    for (int t = 0; t < S_; ++t) {
        const int buf = t & 1;
        const __bf16* hrd = (t & 1) ? hA : hB;
        __bf16*       hwr = (t & 1) ? hB : hA;

        // ---- wait for h_{t-1} from all 64 WGs of this batch group ----
        if (t > 0 && tid == 0) {
            const unsigned* c0 = cnt + ((size_t)(t - 1) * 8) * 32 + bg;
            unsigned s;
            do {
                s = 0;
                #pragma unroll
                for (int u = 0; u < 8; ++u)
                    s += __hip_atomic_load(c0 + u * 32, __ATOMIC_RELAXED,
                                           __HIP_MEMORY_SCOPE_AGENT);
                if (s < 64u) __builtin_amdgcn_s_sleep(1);
            } while (s < 64u);
        }
        __syncthreads();  // b1: h_{t-1} published

        // ---- issue h loads (coherent 8B atomics) ----
        ull hv[16];
        {
            const ull* hs = (const ull*)(hrd + (size_t)(bg * 32) * H_);
            #pragma unroll
            for (int j = 0; j < 16; ++j)
                hv[j] = __hip_atomic_load(&hs[cb * 256 + ccc + 16 * j],
                                          __ATOMIC_RELAXED, __HIP_MEMORY_SCOPE_AGENT);
        }

        // ---- issue x_{t+1} prefetch (consumed after b4) ----
        float4 xf[8];
        const bool pf = (t + 1 < S_);
        if (pf) {
            const float4* xs = (const float4*)(xrow + (size_t)(t + 1) * I_);
            #pragma unroll
            for (int jj = 0; jj < 4; ++jj) {
                const int fi = 2 * ccc + 32 * jj;
                xf[2 * jj]     = xs[fi];
                xf[2 * jj + 1] = xs[fi + 1];
            }
        }

        // ---- land h into LDS ----
        #pragma unroll
        for (int j = 0; j < 16; ++j)
            *(ull*)&hpan[cb * HLD + 4 * (ccc + 16 * j)] = hv[j];
        __syncthreads();  // b2: h panel ready

        // ---- h-part MFMA on top of pipelined x-part ----
        v4f acc0 = accx0;
        v4f acc1 = accx1;
        {
            const __bf16* ap0 = &hpan[l15 * HLD + ks * 512 + q * 8];
            const __bf16* ap1 = ap0 + 16 * HLD;
            #pragma unroll
            for (int j = 0; j < 16; ++j) {
                acc0 = __builtin_amdgcn_mfma_f32_16x16x32_bf16(
                           *(const v8bf*)(ap0 + j * 32), w[8 + j], acc0, 0, 0, 0);
                acc1 = __builtin_amdgcn_mfma_f32_16x16x32_bf16(
                           *(const v8bf*)(ap1 + j * 32), w[8 + j], acc1, 0, 0, 0);
            }
        }

        // ---- store x_{t+1} into the other panel ----
        if (pf) {
            #pragma unroll
            for (int jj = 0; jj < 4; ++jj) {
                const int fi = 2 * ccc + 32 * jj;
                *(v8bf*)&xpan[buf ^ 1][cb * XLD + fi * 4] =
                    cvt8(xf[2 * jj], xf[2 * jj + 1]);
            }
        }

        // ---- exchange gate pre-activations ----
        #pragma unroll
        for (int r = 0; r < 4; ++r) {
            glds[g][ks][q * 4 + r][l15]      = acc0[r] + b0;
            glds[g][ks][16 + q * 4 + r][l15] = acc1[r] + b0;
        }
        __syncthreads();  // b3

        // ---- cell update ----
        const float ig = glds[0][0][cb][ccc] + glds[0][1][cb][ccc];
        const float fg = glds[1][0][cb][ccc] + glds[1][1][cb][ccc];
        const float gg = glds[2][0][cb][ccc] + glds[2][1][cb][ccc];
        const float og = glds[3][0][cb][ccc] + glds[3][1][cb][ccc];

        const float cn = sigm(fg) * creg + sigm(ig) * tanh_fast(gg);
        const float hvv = sigm(og) * tanh_fast(cn);
        creg = cn;

        // ---- publish h_t ----
        const unsigned short us = __builtin_bit_cast(unsigned short, (__bf16)hvv);
        const unsigned nb = __shfl_xor((unsigned)us, 1);
        if (!(tid & 1)) {
            const unsigned pair = (unsigned)us | (nb << 16);
            __hip_atomic_store((unsigned*)&hwr[(size_t)gb * H_ + gc], pair,
                               __ATOMIC_RELAXED, __HIP_MEMORY_SCOPE_AGENT);
        }
        if (t == mylen - 1) out[(size_t)gb * H_ + gc] = hvv;

        __syncthreads();  // b4: drains h stores + xpan writes (vmcnt(0)+barrier)
        if (tid == 0)
            __hip_atomic_fetch_add(cnt + ((size_t)t * 8 + (cg & 7)) * 32 + bg, 1u,
                                   __ATOMIC_RELAXED, __HIP_MEMORY_SCOPE_AGENT);

        // ---- pipelined x-part MFMA for t+1 (fills the poll window) ----
        if (pf) {
            accx0 = (v4f){0.f, 0.f, 0.f, 0.f};
            accx1 = (v4f){0.f, 0.f, 0.f, 0.f};
            const __bf16* ap0 = &xpan[buf ^ 1][l15 * XLD + ks * 256 + q * 8];
            const __bf16* ap1 = ap0 + 16 * XLD;
            #pragma unroll
            for (int j = 0; j < 8; ++j) {
                accx0 = __builtin_amdgcn_mfma_f32_16x16x32_bf16(
                            *(const v8bf*)(ap0 + j * 32), w[j], accx0, 0, 0, 0);
                accx1 = __builtin_amdgcn_mfma_f32_16x16x32_bf16(
                            *(const v8bf*)(ap1 + j * 32), w[j], accx1, 0, 0, 0);
            }
        }
    }
}

extern "C" void kernel_launch(void* const* d_in, const int* in_sizes, int n_in,
                              void* d_out, int out_size, void* d_ws, size_t ws_size,
                              hipStream_t stream) {
    const float* seq = (const float*)d_in[0];
    const int*   len = (const int*)d_in[1];
    const float* Wih = (const float*)d_in[2];
    const float* Whh = (const float*)d_in[3];
    const float* bih = (const float*)d_in[4];
    const float* bhh = (const float*)d_in[5];
    float* out = (float*)d_out;

    char* ws = (char*)d_ws;
    __bf16*   Wc  = (__bf16*)ws;                          // 12,582,912 B
    __bf16*   hA  = (__bf16*)(ws + 12582912);             //    262,144 B
    __bf16*   hB  = (__bf16*)(ws + 12845056);             //    262,144 B
    unsigned* cnt = (unsigned*)(ws + 13107200);           //  1,048,576 B

    hipMemsetAsync(hA, 0, 2 * (size_t)B_ * H_ * sizeof(__bf16), stream);  // hA+hB
    hipMemsetAsync(cnt, 0, (size_t)S_ * 8 * 32 * sizeof(unsigned), stream);

    lstm_pack<<<dim3(3072), dim3(256), 0, stream>>>(Wih, Whh, Wc);

    void* args[] = {(void*)&seq, (void*)&len, (void*)&Wc, (void*)&bih,
                    (void*)&bhh, (void*)&out, (void*)&hA, (void*)&hB, (void*)&cnt};
    hipError_t e = hipLaunchCooperativeKernel((void*)lstm_persist, dim3(NWG),
                                              dim3(NTHR), args, 0, stream);
    if (e != hipSuccess) {
        lstm_persist<<<dim3(NWG), dim3(NTHR), 0, stream>>>(seq, len, Wc, bih,
                                                           bhh, out, hA, hB, cnt);
    }
}